// Round 4
// baseline (27298.196 us; speedup 1.0000x reference)
//
#include <hip/hip_runtime.h>
#include <cstdint>
#include <cstddef>

using u16 = unsigned short;
using u32 = unsigned int;

typedef __attribute__((ext_vector_type(8)))  __bf16 bf16x8;
typedef __attribute__((ext_vector_type(16))) float  f32x16;

constexpr int kB   = 512;
constexpr int kT   = 180;
constexpr int kH   = 768;
constexpr int NBLK = 192;   // 3 layers * (4 m-tiles * 16 n-tiles)

constexpr int L0N  = 16 * 192 * 832;    // layer0 packed weight elems
constexpr int L12N = 16 * 192 * 1536;   // layer1/2 packed weight elems

// workspace layout (bytes)
constexpr size_t RING_SZ = (size_t)4 * kB * kH * 2;            // 3,145,728
constexpr size_t OFF_R0  = 256;
constexpr size_t OFF_R1  = OFF_R0 + RING_SZ;
constexpr size_t OFF_R2  = OFF_R1 + RING_SZ;
constexpr size_t OFF_PB  = OFF_R2 + RING_SZ;                   // 9,437,440
constexpr size_t OFF_XT  = OFF_PB + (size_t)3 * 3072 * 4;
constexpr size_t OFF_W0  = OFF_XT + (size_t)kT * kB * 64 * 2;
constexpr size_t OFF_W1  = OFF_W0 + (size_t)L0N * 2;
constexpr size_t OFF_W2  = OFF_W1 + (size_t)L12N * 2;
constexpr size_t WS_NEED = OFF_W2 + (size_t)L12N * 2;          // ~45.3 MB

__device__ __forceinline__ float bf2f(u16 u) {
  union { u32 i; float f; } v; v.i = ((u32)u) << 16; return v.f;
}
__device__ __forceinline__ u16 f2bf(float f) {
  union { float f; u32 i; } v; v.f = f;
  u32 r = v.i + 0x7fffu + ((v.i >> 16) & 1u);
  return (u16)(r >> 16);
}

// ---------------------------------------------------------------- zero
__global__ void k_zero(uint4* p, int n) {
  uint4 z = make_uint4(0u, 0u, 0u, 0u);
  for (int i = blockIdx.x * 256 + threadIdx.x; i < n; i += gridDim.x * 256) p[i] = z;
}

// ---------------------------------------------------------------- weight pack
// Packed layout per layer: [ntile(16)][pcol(192)][K] bf16, K-contiguous per column.
// pcol = gate*48 + hc  (gate order i,f,g,o), global gate col = gate*768 + ntile*48 + hc.
// Layer0 K = 832: rows 0..39 = w_ih0, 40..63 = 0 pad, 64..831 = w_hh0.
// Layer1/2 K = 1536: rows 0..767 = w_ih, 768..1535 = w_hh.
__global__ void k_pack_w(const float* __restrict__ wih0, const float* __restrict__ whh0,
                         const float* __restrict__ wih1, const float* __restrict__ whh1,
                         const float* __restrict__ wih2, const float* __restrict__ whh2,
                         u16* __restrict__ W0, u16* __restrict__ W1, u16* __restrict__ W2) {
  int idx = blockIdx.x * 256 + threadIdx.x;
  if (idx < L0N) {
    int col = idx / 832, k = idx - col * 832;
    int ntile = col / 192, p = col - ntile * 192;
    int g = p / 48, hc = p - g * 48;
    int gcol = g * 768 + ntile * 48 + hc;
    float v = (k < 40) ? wih0[gcol * 40 + k]
                       : ((k < 64) ? 0.f : whh0[(size_t)gcol * 768 + (k - 64)]);
    W0[idx] = f2bf(v);
  } else if (idx < L0N + L12N) {
    int li = idx - L0N;
    int col = li / 1536, k = li - col * 1536;
    int ntile = col / 192, p = col - ntile * 192;
    int g = p / 48, hc = p - g * 48;
    int gcol = g * 768 + ntile * 48 + hc;
    float v = (k < 768) ? wih1[(size_t)gcol * 768 + k] : whh1[(size_t)gcol * 768 + (k - 768)];
    W1[li] = f2bf(v);
  } else {
    int li = idx - (L0N + L12N);
    int col = li / 1536, k = li - col * 1536;
    int ntile = col / 192, p = col - ntile * 192;
    int g = p / 48, hc = p - g * 48;
    int gcol = g * 768 + ntile * 48 + hc;
    float v = (k < 768) ? wih2[(size_t)gcol * 768 + k] : whh2[(size_t)gcol * 768 + (k - 768)];
    W2[li] = f2bf(v);
  }
}

// ---------------------------------------------------------------- bias pack
__global__ void k_pack_b(const float* __restrict__ bi0, const float* __restrict__ bh0,
                         const float* __restrict__ bi1, const float* __restrict__ bh1,
                         const float* __restrict__ bi2, const float* __restrict__ bh2,
                         float* __restrict__ pbo) {
  int idx = blockIdx.x * 256 + threadIdx.x;   // 3*3072
  int l = idx / 3072, r = idx - l * 3072;
  int ntile = r / 192, p = r - ntile * 192;
  int g = p / 48, hc = p - g * 48;
  int gcol = g * 768 + ntile * 48 + hc;
  const float* bi = (l == 0) ? bi0 : ((l == 1) ? bi1 : bi2);
  const float* bh = (l == 0) ? bh0 : ((l == 1) ? bh1 : bh2);
  pbo[idx] = bi[gcol] + bh[gcol];
}

// ---------------------------------------------------------------- x transpose [B,T,40] -> [T,B,64pad] bf16
__global__ void k_xT(const float* __restrict__ x, u16* __restrict__ xT) {
  int idx = blockIdx.x * 256 + threadIdx.x;    // 180*512*64
  int t = idx / (512 * 64);
  int r = idx - t * 512 * 64;
  int b = r >> 6, j = r & 63;
  float v = (j < 40) ? x[((size_t)b * 180 + t) * 40 + j] : 0.f;
  xT[idx] = f2bf(v);
}

// ---------------------------------------------------------------- persistent pipelined LSTM
// Grid = 192 blocks x 256 threads (cooperative). Block: layer=bid/64, mt=(bid%64)>>4,
// ntile=bid&15. Super-step s: layer l computes t = s - l. Grid barrier per super-step.
//
// K-loop (R2 dataflow + register prefetch, ordered so the compiler's
// vmcnt(0)-before-s_barrier does NOT kill the overlap):
//   sync -> ds_write(regs chunk c) -> sync -> ISSUE global loads chunk c+1 -> MFMA(c)
// Loads for c+1 fly under MFMA(c); iteration c+1's first sync finds them landed.
// LDS identical to R2 (proven correct, 0 bank conflicts): A[128][72] | B[192][72];
// epilogue scratch [128][192] bf16 aliases; pbias after. Total 49,920 B (<64K).
__global__ __launch_bounds__(256, 2) void k_lstm(
    const u16* __restrict__ xT,
    u16* __restrict__ ring0, u16* __restrict__ ring1, u16* __restrict__ ring2,
    const u16* __restrict__ W0, const u16* __restrict__ W1, const u16* __restrict__ W2,
    const float* __restrict__ pb, u32* __restrict__ bar) {
  __shared__ __align__(16) unsigned char smem[49152 + 768];
  u16*   Asm = (u16*)smem;                 // [128][72]
  u16*   Bsm = (u16*)(smem + 18432);       // [192][72]
  u16*   scr = (u16*)smem;                 // [128][192] epilogue scratch (aliases)
  float* pbs = (float*)(smem + 49152);

  const int tid   = threadIdx.x;
  const int bid   = blockIdx.x;
  const int layer = bid / 64;
  const int sub   = bid - layer * 64;
  const int mt    = sub >> 4;
  const int ntile = sub & 15;
  const int mrow0 = mt * 128;

  const u16* Wl      = (layer == 0) ? W0 : ((layer == 1) ? W1 : W2);
  const int  Kin     = (layer == 0) ? 64 : 768;
  const int  Kl      = Kin + 768;
  const int  nch     = Kl >> 6;
  const u16* inseq   = (layer == 1) ? ring0 : ring1;   // only used for layers 1,2
  const int  instr_  = (layer == 0) ? 64 : kH;
  u16*       ringS   = (layer == 0) ? ring0 : ((layer == 1) ? ring1 : ring2);
  const u16* bbase0  = Wl + (size_t)(ntile * 192) * Kl;

  for (int i = tid; i < 192; i += 256) pbs[i] = pb[layer * 3072 + ntile * 192 + i];

  const int wid = tid >> 6, lane = tid & 63;
  const int wm = wid & 1, wn = wid >> 1;
  const int l31 = lane & 31, lhi = lane >> 5;
  const int srow = tid >> 3, skc = tid & 7;   // staging decomposition

  float c_reg[24];
#pragma unroll
  for (int i = 0; i < 24; i++) c_reg[i] = 0.f;

  for (int s = 0; s < kT + 2; ++s) {
    const int t = s - layer;
    if (t >= 0 && t < kT) {
      f32x16 acc[2][3];
#pragma unroll
      for (int mi = 0; mi < 2; mi++)
#pragma unroll
        for (int ni = 0; ni < 3; ni++)
#pragma unroll
          for (int r = 0; r < 16; r++) acc[mi][ni][r] = 0.f;

      const u16* inb = (layer == 0) ? (xT + (size_t)t * kB * 64)
                                    : (inseq + (size_t)(t & 3) * kB * kH);
      const u16* rec = ringS + (size_t)((t - 1) & 3) * kB * kH;   // t=0 -> slot 3 (zeros)

      uint4 ra[4], rb[6];
      // issue global loads for chunk c into prefetch regs (no LDS touch)
      auto stage_regs = [&](int c) {
        const int  kbase = c << 6;
        const bool isin  = kbase < Kin;
        const u16* abase = isin ? inb : rec;
        const int  astr  = isin ? instr_ : kH;
        const int  koff  = isin ? kbase : (kbase - Kin);
#pragma unroll
        for (int i = 0; i < 4; i++) {
          int row = srow + i * 32;
          ra[i] = *(const uint4*)(abase + (size_t)(mrow0 + row) * astr + koff + skc * 8);
        }
        const u16* bb = bbase0 + kbase;
#pragma unroll
        for (int i = 0; i < 6; i++) {
          int col = srow + i * 32;
          rb[i] = *(const uint4*)(bb + (size_t)col * Kl + skc * 8);
        }
      };

      stage_regs(0);
      for (int c = 0; c < nch; ++c) {
        __syncthreads();   // LDS free (prev chunk's reads done); drains in-flight loads
        // regs -> LDS (same layout as R2: pitch 72, no swizzle)
#pragma unroll
        for (int i = 0; i < 4; i++)
          *(uint4*)(Asm + (srow + i * 32) * 72 + skc * 8) = ra[i];
#pragma unroll
        for (int i = 0; i < 6; i++)
          *(uint4*)(Bsm + (srow + i * 32) * 72 + skc * 8) = rb[i];
        __syncthreads();   // lgkm drain: all waves see chunk c in LDS
        if (c + 1 < nch) stage_regs(c + 1);   // loads fly under the MFMAs below
        // wave tile 64x96: 2x3 of 32x32, K-chunk = 4 x K16
#pragma unroll
        for (int kk = 0; kk < 4; kk++) {
          const int ko = kk * 16 + lhi * 8;
          bf16x8 a0 = *(const bf16x8*)(Asm + (wm * 64 +      l31) * 72 + ko);
          bf16x8 a1 = *(const bf16x8*)(Asm + (wm * 64 + 32 + l31) * 72 + ko);
          bf16x8 b0 = *(const bf16x8*)(Bsm + (wn * 96 +      l31) * 72 + ko);
          bf16x8 b1 = *(const bf16x8*)(Bsm + (wn * 96 + 32 + l31) * 72 + ko);
          bf16x8 b2 = *(const bf16x8*)(Bsm + (wn * 96 + 64 + l31) * 72 + ko);
          acc[0][0] = __builtin_amdgcn_mfma_f32_32x32x16_bf16(a0, b0, acc[0][0], 0, 0, 0);
          acc[0][1] = __builtin_amdgcn_mfma_f32_32x32x16_bf16(a0, b1, acc[0][1], 0, 0, 0);
          acc[0][2] = __builtin_amdgcn_mfma_f32_32x32x16_bf16(a0, b2, acc[0][2], 0, 0, 0);
          acc[1][0] = __builtin_amdgcn_mfma_f32_32x32x16_bf16(a1, b0, acc[1][0], 0, 0, 0);
          acc[1][1] = __builtin_amdgcn_mfma_f32_32x32x16_bf16(a1, b1, acc[1][1], 0, 0, 0);
          acc[1][2] = __builtin_amdgcn_mfma_f32_32x32x16_bf16(a1, b2, acc[1][2], 0, 0, 0);
        }
      }
      __syncthreads();
      // epilogue: bias + nonlinearity (C/D: col=lane&31, row=(r&3)+8*(r>>2)+4*lhi)
#pragma unroll
      for (int mi = 0; mi < 2; mi++) {
#pragma unroll
        for (int ni = 0; ni < 3; ni++) {
          const int pcol = wn * 96 + ni * 32 + l31;
          const int g = pcol / 48;
          const float bias = pbs[pcol];
#pragma unroll
          for (int r = 0; r < 16; r++) {
            const int rowl = wm * 64 + mi * 32 + (r & 3) + ((r >> 2) << 3) + (lhi << 2);
            float v = acc[mi][ni][r] + bias;
            v = (g == 2) ? tanhf(v) : (1.f / (1.f + __expf(-v)));
            scr[rowl * 192 + pcol] = f2bf(v);
          }
        }
      }
      __syncthreads();
      // pointwise LSTM cell update; c stays in registers (block owns fixed tile)
      u16* hout = ringS + (size_t)(t & 3) * kB * kH;
#pragma unroll
      for (int jj = 0; jj < 24; jj++) {
        const int idx = jj * 256 + tid;        // 6144 = 128 rows x 48 h-cols
        const int row = idx / 48;
        const int hc  = idx - row * 48;
        const float iv = bf2f(scr[row * 192       + hc]);
        const float fv = bf2f(scr[row * 192 +  48 + hc]);
        const float gv = bf2f(scr[row * 192 +  96 + hc]);
        const float ov = bf2f(scr[row * 192 + 144 + hc]);
        const float cn = fv * c_reg[jj] + iv * gv;
        c_reg[jj] = cn;
        hout[(size_t)(mrow0 + row) * kH + ntile * 48 + hc] = f2bf(ov * tanhf(cn));
      }
    }
    // ---- grid barrier (monotonic counter, release/acquire, agent scope) ----
    // BOUNDED spin: degrade to wrong answer, never hang the queue.
    __syncthreads();   // drains vmcnt before s_barrier -> block's stores at L2
    if (tid == 0) {
      __hip_atomic_fetch_add(bar, 1u, __ATOMIC_RELEASE, __HIP_MEMORY_SCOPE_AGENT);
      const u32 goal = (u32)(s + 1) * (u32)NBLK;
      u32 tries = 0;
      while (__hip_atomic_load(bar, __ATOMIC_RELAXED, __HIP_MEMORY_SCOPE_AGENT) < goal) {
        __builtin_amdgcn_s_sleep(8);
        if (++tries > 100000u) break;   // ~20 ms; normal wait is ~us
      }
      __threadfence();
    }
    __syncthreads();
  }
}

// ---------------------------------------------------------------- projection + L2 norm
__global__ __launch_bounds__(256) void k_proj(const u16* __restrict__ hlast,
                                              const float* __restrict__ pw,
                                              const float* __restrict__ pbv,
                                              float* __restrict__ out) {
  __shared__ float hs[8 * 768];
  __shared__ float wred[4 * 8];
  __shared__ float inv[8];
  const int tid = threadIdx.x;
  const int r0 = blockIdx.x * 8;
  for (int i = tid; i < 8 * 768; i += 256) hs[i] = bf2f(hlast[(size_t)r0 * 768 + i]);
  __syncthreads();
  float acc[8];
#pragma unroll
  for (int r = 0; r < 8; r++) acc[r] = 0.f;
  const float* wrow = pw + (size_t)tid * 768;
  for (int k = 0; k < 768; k++) {
    float w = wrow[k];
#pragma unroll
    for (int r = 0; r < 8; r++) acc[r] += hs[r * 768 + k] * w;
  }
  const float bv = pbv[tid];
#pragma unroll
  for (int r = 0; r < 8; r++) acc[r] += bv;
  const int lane = tid & 63, w4 = tid >> 6;
#pragma unroll
  for (int r = 0; r < 8; r++) {
    float v = acc[r] * acc[r];
#pragma unroll
    for (int off = 32; off > 0; off >>= 1) v += __shfl_xor(v, off);
    if (lane == 0) wred[w4 * 8 + r] = v;
  }
  __syncthreads();
  if (tid < 8) {
    float sum = wred[tid] + wred[8 + tid] + wred[16 + tid] + wred[24 + tid];
    inv[tid] = 1.f / sqrtf(sum);
  }
  __syncthreads();
#pragma unroll
  for (int r = 0; r < 8; r++) out[(size_t)(r0 + r) * 256 + tid] = acc[r] * inv[r];
}

// ---------------------------------------------------------------- host
extern "C" void kernel_launch(void* const* d_in, const int* in_sizes, int n_in,
                              void* d_out, int out_size, void* d_ws, size_t ws_size,
                              hipStream_t stream) {
  const float* x    = (const float*)d_in[0];
  const float* wih0 = (const float*)d_in[1];
  const float* whh0 = (const float*)d_in[2];
  const float* bi0  = (const float*)d_in[3];
  const float* bh0  = (const float*)d_in[4];
  const float* wih1 = (const float*)d_in[5];
  const float* whh1 = (const float*)d_in[6];
  const float* bi1  = (const float*)d_in[7];
  const float* bh1  = (const float*)d_in[8];
  const float* wih2 = (const float*)d_in[9];
  const float* whh2 = (const float*)d_in[10];
  const float* bi2  = (const float*)d_in[11];
  const float* bh2  = (const float*)d_in[12];
  const float* pw   = (const float*)d_in[13];
  const float* pbv  = (const float*)d_in[14];

  // Workspace-size guard: if insufficient, bail (clean wrong answer, no OOB).
  if (ws_size < WS_NEED) return;

  char* ws  = (char*)d_ws;
  u32*  bar = (u32*)(ws + 0);
  u16*  r0  = (u16*)(ws + OFF_R0);
  u16*  r1  = (u16*)(ws + OFF_R1);
  u16*  r2  = (u16*)(ws + OFF_R2);
  float* pb = (float*)(ws + OFF_PB);
  u16*  xT  = (u16*)(ws + OFF_XT);
  u16*  W0  = (u16*)(ws + OFF_W0);
  u16*  W1  = (u16*)(ws + OFF_W1);
  u16*  W2  = (u16*)(ws + OFF_W2);

  // zero barrier + rings (first OFF_PB bytes)
  hipLaunchKernelGGL(k_zero, dim3(512), dim3(256), 0, stream,
                     (uint4*)ws, (int)(OFF_PB / 16));
  hipLaunchKernelGGL(k_pack_w, dim3((L0N + 2 * L12N) / 256), dim3(256), 0, stream,
                     wih0, whh0, wih1, whh1, wih2, whh2, W0, W1, W2);
  hipLaunchKernelGGL(k_pack_b, dim3(36), dim3(256), 0, stream,
                     bi0, bh0, bi1, bh1, bi2, bh2, pb);
  hipLaunchKernelGGL(k_xT, dim3(kT * kB * 64 / 256), dim3(256), 0, stream, x, xT);

  // cooperative launch -> all 192 blocks co-resident (grid barrier is safe)
  {
    const u16* xTc = xT; const float* pbc = pb;
    const u16 *W0c = W0, *W1c = W1, *W2c = W2;
    u16 *r0m = r0, *r1m = r1, *r2m = r2; u32* barm = bar;
    void* kargs[] = {(void*)&xTc, (void*)&r0m, (void*)&r1m, (void*)&r2m,
                     (void*)&W0c, (void*)&W1c, (void*)&W2c, (void*)&pbc, (void*)&barm};
    hipLaunchCooperativeKernel((void*)k_lstm, dim3(NBLK), dim3(256), kargs, 0, stream);
  }

  hipLaunchKernelGGL(k_proj, dim3(64), dim3(256), 0, stream,
                     r2 + (size_t)3 * kB * kH, pw, pbv, (float*)d_out);
}

// Round 5
// 10728.149 us; speedup vs baseline: 2.5445x; 2.5445x over previous
//
#include <hip/hip_runtime.h>
#include <cstdint>
#include <cstddef>

using u16 = unsigned short;
using u32 = unsigned int;

typedef __attribute__((ext_vector_type(8)))  __bf16 bf16x8;
typedef __attribute__((ext_vector_type(16))) float  f32x16;

constexpr int kB   = 512;
constexpr int kT   = 180;
constexpr int kH   = 768;
constexpr int NBLK = 192;   // 3 layers * (4 m-tiles * 16 n-tiles)

constexpr int L0N  = 16 * 192 * 832;    // layer0 packed weight elems
constexpr int L12N = 16 * 192 * 1536;   // layer1/2 packed weight elems

// workspace layout (bytes)
constexpr size_t RING_SZ = (size_t)4 * kB * kH * 2;            // 3,145,728
constexpr size_t OFF_R0  = 256;
constexpr size_t OFF_R1  = OFF_R0 + RING_SZ;
constexpr size_t OFF_R2  = OFF_R1 + RING_SZ;
constexpr size_t OFF_PB  = OFF_R2 + RING_SZ;                   // 9,437,440
constexpr size_t OFF_XT  = OFF_PB + (size_t)3 * 3072 * 4;
constexpr size_t OFF_W0  = OFF_XT + (size_t)kT * kB * 64 * 2;
constexpr size_t OFF_W1  = OFF_W0 + (size_t)L0N * 2;
constexpr size_t OFF_W2  = OFF_W1 + (size_t)L12N * 2;
constexpr size_t WS_NEED = OFF_W2 + (size_t)L12N * 2;          // ~45.3 MB

__device__ __forceinline__ float bf2f(u16 u) {
  union { u32 i; float f; } v; v.i = ((u32)u) << 16; return v.f;
}
__device__ __forceinline__ u16 f2bf(float f) {
  union { float f; u32 i; } v; v.f = f;
  u32 r = v.i + 0x7fffu + ((v.i >> 16) & 1u);
  return (u16)(r >> 16);
}

// async global->LDS, 16B per lane. HW semantics: wave-uniform LDS base
// (readfirstlane) + lane*16. All our dests are lane-linear by construction.
typedef __attribute__((address_space(1))) const u32 as1_u32;
typedef __attribute__((address_space(3))) u32 as3_u32;
__device__ __forceinline__ void gload_lds16(const u16* g, u16* l) {
  __builtin_amdgcn_global_load_lds((as1_u32*)g, (as3_u32*)l, 16, 0, 0);
}

// ---------------------------------------------------------------- zero
__global__ void k_zero(uint4* p, int n) {
  uint4 z = make_uint4(0u, 0u, 0u, 0u);
  for (int i = blockIdx.x * 256 + threadIdx.x; i < n; i += gridDim.x * 256) p[i] = z;
}

// ---------------------------------------------------------------- weight pack
// Packed layout per layer: [ntile(16)][pcol(192)][K] bf16, K-contiguous per column.
// pcol = gate*48 + hc  (gate order i,f,g,o), global gate col = gate*768 + ntile*48 + hc.
// Layer0 K = 832: rows 0..39 = w_ih0, 40..63 = 0 pad, 64..831 = w_hh0.
// Layer1/2 K = 1536: rows 0..767 = w_ih, 768..1535 = w_hh.
__global__ void k_pack_w(const float* __restrict__ wih0, const float* __restrict__ whh0,
                         const float* __restrict__ wih1, const float* __restrict__ whh1,
                         const float* __restrict__ wih2, const float* __restrict__ whh2,
                         u16* __restrict__ W0, u16* __restrict__ W1, u16* __restrict__ W2) {
  int idx = blockIdx.x * 256 + threadIdx.x;
  if (idx < L0N) {
    int col = idx / 832, k = idx - col * 832;
    int ntile = col / 192, p = col - ntile * 192;
    int g = p / 48, hc = p - g * 48;
    int gcol = g * 768 + ntile * 48 + hc;
    float v = (k < 40) ? wih0[gcol * 40 + k]
                       : ((k < 64) ? 0.f : whh0[(size_t)gcol * 768 + (k - 64)]);
    W0[idx] = f2bf(v);
  } else if (idx < L0N + L12N) {
    int li = idx - L0N;
    int col = li / 1536, k = li - col * 1536;
    int ntile = col / 192, p = col - ntile * 192;
    int g = p / 48, hc = p - g * 48;
    int gcol = g * 768 + ntile * 48 + hc;
    float v = (k < 768) ? wih1[(size_t)gcol * 768 + k] : whh1[(size_t)gcol * 768 + (k - 768)];
    W1[li] = f2bf(v);
  } else {
    int li = idx - (L0N + L12N);
    int col = li / 1536, k = li - col * 1536;
    int ntile = col / 192, p = col - ntile * 192;
    int g = p / 48, hc = p - g * 48;
    int gcol = g * 768 + ntile * 48 + hc;
    float v = (k < 768) ? wih2[(size_t)gcol * 768 + k] : whh2[(size_t)gcol * 768 + (k - 768)];
    W2[li] = f2bf(v);
  }
}

// ---------------------------------------------------------------- bias pack
__global__ void k_pack_b(const float* __restrict__ bi0, const float* __restrict__ bh0,
                         const float* __restrict__ bi1, const float* __restrict__ bh1,
                         const float* __restrict__ bi2, const float* __restrict__ bh2,
                         float* __restrict__ pbo) {
  int idx = blockIdx.x * 256 + threadIdx.x;   // 3*3072
  int l = idx / 3072, r = idx - l * 3072;
  int ntile = r / 192, p = r - ntile * 192;
  int g = p / 48, hc = p - g * 48;
  int gcol = g * 768 + ntile * 48 + hc;
  const float* bi = (l == 0) ? bi0 : ((l == 1) ? bi1 : bi2);
  const float* bh = (l == 0) ? bh0 : ((l == 1) ? bh1 : bh2);
  pbo[idx] = bi[gcol] + bh[gcol];
}

// ---------------------------------------------------------------- x transpose [B,T,40] -> [T,B,64pad] bf16
__global__ void k_xT(const float* __restrict__ x, u16* __restrict__ xT) {
  int idx = blockIdx.x * 256 + threadIdx.x;    // 180*512*64
  int t = idx / (512 * 64);
  int r = idx - t * 512 * 64;
  int b = r >> 6, j = r & 63;
  float v = (j < 40) ? x[((size_t)b * 180 + t) * 40 + j] : 0.f;
  xT[idx] = f2bf(v);
}

// ---------------------------------------------------------------- persistent pipelined LSTM
// Grid = 192 blocks x 256 threads (cooperative). Block: layer=bid/64, mt=(bid%64)>>4,
// ntile=bid&15. Super-step s: layer l computes t = s - l. Grid barrier per super-step.
//
// K-loop: AITER-style. K-chunks of 32; 3 stage buffers (20 KB each); staging via
// global_load_lds (zero VGPR cost — R4 showed VGPR prefetch spills to scratch).
// Two chunks always in flight (10 glds/thread = 40 KB/block) — in-flight-bw
// ~137 B/cyc/CU > 56 B/cyc L2 ceiling, so we are BW-limited not latency-limited.
// Per chunk: s_waitcnt vmcnt(5) [own chunk landed, keep next 2 flying] ->
// raw s_barrier [all waves landed theirs] -> issue chunk c+2 -> MFMA chunk c.
// NO __syncthreads in the K-loop: its vmcnt(0) would drain the prefetch queue.
//
// LDS: 3 stages x 20,480 B @0 | pbias @61,440. Stage: A[128][32] (4 KB rows of 64 B,
// 4 slots/row) + B[192][32] @+8 KB. 16B slot sp of row r holds k-octet (sp ^ (r&3))
// -> lane-linear glds dests AND spread frag reads. Epilogue scratch [128][192] bf16
// aliases stages. Total 62,208 B < 64 KB static limit (R3's 82 KB broke the launch).
__global__ __launch_bounds__(256, 2) void k_lstm(
    const u16* __restrict__ xT,
    u16* __restrict__ ring0, u16* __restrict__ ring1, u16* __restrict__ ring2,
    const u16* __restrict__ W0, const u16* __restrict__ W1, const u16* __restrict__ W2,
    const float* __restrict__ pb, u32* __restrict__ bar) {
  __shared__ __align__(16) unsigned char smem[61440 + 768];
  u16*   scr = (u16*)smem;                 // [128][192] epilogue scratch (aliases stages)
  float* pbs = (float*)(smem + 61440);

  const int tid   = threadIdx.x;
  const int bid   = blockIdx.x;
  const int layer = bid / 64;
  const int sub   = bid - layer * 64;
  const int mt    = sub >> 4;
  const int ntile = sub & 15;
  const int mrow0 = mt * 128;

  const u16* Wl      = (layer == 0) ? W0 : ((layer == 1) ? W1 : W2);
  const int  Kin     = (layer == 0) ? 64 : 768;
  const int  Kl      = Kin + 768;
  const int  nch     = Kl >> 5;                        // K-chunks of 32
  const u16* inseq   = (layer == 1) ? ring0 : ring1;   // only used for layers 1,2
  const int  instr_  = (layer == 0) ? 64 : kH;
  u16*       ringS   = (layer == 0) ? ring0 : ((layer == 1) ? ring1 : ring2);
  const u16* bbase0  = Wl + (size_t)(ntile * 192) * Kl;

  for (int i = tid; i < 192; i += 256) pbs[i] = pb[layer * 3072 + ntile * 192 + i];

  const int wid = tid >> 6, lane = tid & 63;
  const int wm = wid & 1, wn = wid >> 1;
  const int l31 = lane & 31, lhi = lane >> 5;

  float c_reg[24];
#pragma unroll
  for (int i = 0; i < 24; i++) c_reg[i] = 0.f;

  for (int s = 0; s < kT + 2; ++s) {
    const int t = s - layer;
    if (t >= 0 && t < kT) {
      f32x16 acc[2][3];
#pragma unroll
      for (int mi = 0; mi < 2; mi++)
#pragma unroll
        for (int ni = 0; ni < 3; ni++)
#pragma unroll
          for (int r = 0; r < 16; r++) acc[mi][ni][r] = 0.f;

      const u16* inb = (layer == 0) ? (xT + (size_t)t * kB * 64)
                                    : (inseq + (size_t)(t & 3) * kB * kH);
      const u16* rec = ringS + (size_t)((t - 1) & 3) * kB * kH;   // t=0 -> slot 3 (zeros)

      // issue all glds for K-chunk c into stage buffer st (5 x 16B per thread)
      auto stage = [&](int c, int st) {
        const int  kbase = c << 5;
        const bool isin  = kbase < Kin;
        const u16* abase = isin ? inb : rec;
        const int  astr  = isin ? instr_ : kH;
        const int  koff  = isin ? kbase : (kbase - Kin);
        u16* sb = (u16*)(smem + st * 20480);
        // A: 512 slots (128 rows x 4), dest slot d = tid + k*256 (lane-linear)
#pragma unroll
        for (int k = 0; k < 2; k++) {
          const int d = tid + k * 256;
          const int row = d >> 2, sp = d & 3;
          const int so = sp ^ (row & 3);
          gload_lds16(abase + (size_t)(mrow0 + row) * astr + koff + so * 8,
                      sb + (size_t)d * 8);
        }
        // B: 768 slots (192 cols x 4)
#pragma unroll
        for (int k = 0; k < 3; k++) {
          const int e = tid + k * 256;
          const int col = e >> 2, sp = e & 3;
          const int so = sp ^ (col & 3);
          gload_lds16(bbase0 + (size_t)col * Kl + kbase + so * 8,
                      sb + 4096 + (size_t)e * 8);
        }
      };

      stage(0, 0);
      stage(1, 1);
      for (int c = 0; c < nch; ++c) {
        __asm__ volatile("" ::: "memory");
        if (c == nch - 1) __builtin_amdgcn_s_waitcnt(0xF70);  // vmcnt(0)
        else              __builtin_amdgcn_s_waitcnt(0xF75);  // vmcnt(5): keep 2 chunks flying
        __builtin_amdgcn_s_barrier();
        __asm__ volatile("" ::: "memory");
        if (c + 2 < nch) stage(c + 2, (c + 2) % 3);
        const u16* sb = (const u16*)(smem + (c % 3) * 20480);
        const u16* sA = sb;
        const u16* sB = sb + 4096;
#pragma unroll
        for (int kk = 0; kk < 2; kk++) {
          const int sw = (((kk << 1) | lhi) ^ (l31 & 3)) << 3;  // swizzled 16B slot
          bf16x8 a0 = *(const bf16x8*)(sA + (wm * 64 +      l31) * 32 + sw);
          bf16x8 a1 = *(const bf16x8*)(sA + (wm * 64 + 32 + l31) * 32 + sw);
          bf16x8 b0 = *(const bf16x8*)(sB + (wn * 96 +      l31) * 32 + sw);
          bf16x8 b1 = *(const bf16x8*)(sB + (wn * 96 + 32 + l31) * 32 + sw);
          bf16x8 b2 = *(const bf16x8*)(sB + (wn * 96 + 64 + l31) * 32 + sw);
          acc[0][0] = __builtin_amdgcn_mfma_f32_32x32x16_bf16(a0, b0, acc[0][0], 0, 0, 0);
          acc[0][1] = __builtin_amdgcn_mfma_f32_32x32x16_bf16(a0, b1, acc[0][1], 0, 0, 0);
          acc[0][2] = __builtin_amdgcn_mfma_f32_32x32x16_bf16(a0, b2, acc[0][2], 0, 0, 0);
          acc[1][0] = __builtin_amdgcn_mfma_f32_32x32x16_bf16(a1, b0, acc[1][0], 0, 0, 0);
          acc[1][1] = __builtin_amdgcn_mfma_f32_32x32x16_bf16(a1, b1, acc[1][1], 0, 0, 0);
          acc[1][2] = __builtin_amdgcn_mfma_f32_32x32x16_bf16(a1, b2, acc[1][2], 0, 0, 0);
        }
      }
      __syncthreads();   // K-loop done (vmcnt=0); protect LDS before scr overwrite
      // epilogue: bias + nonlinearity (C/D: col=lane&31, row=(r&3)+8*(r>>2)+4*lhi)
#pragma unroll
      for (int mi = 0; mi < 2; mi++) {
#pragma unroll
        for (int ni = 0; ni < 3; ni++) {
          const int pcol = wn * 96 + ni * 32 + l31;
          const int g = pcol / 48;
          const float bias = pbs[pcol];
#pragma unroll
          for (int r = 0; r < 16; r++) {
            const int rowl = wm * 64 + mi * 32 + (r & 3) + ((r >> 2) << 3) + (lhi << 2);
            float v = acc[mi][ni][r] + bias;
            v = (g == 2) ? tanhf(v) : (1.f / (1.f + __expf(-v)));
            scr[rowl * 192 + pcol] = f2bf(v);
          }
        }
      }
      __syncthreads();
      // pointwise LSTM cell update; c stays in registers (block owns fixed tile)
      u16* hout = ringS + (size_t)(t & 3) * kB * kH;
#pragma unroll
      for (int jj = 0; jj < 24; jj++) {
        const int idx = jj * 256 + tid;        // 6144 = 128 rows x 48 h-cols
        const int row = idx / 48;
        const int hc  = idx - row * 48;
        const float iv = bf2f(scr[row * 192       + hc]);
        const float fv = bf2f(scr[row * 192 +  48 + hc]);
        const float gv = bf2f(scr[row * 192 +  96 + hc]);
        const float ov = bf2f(scr[row * 192 + 144 + hc]);
        const float cn = fv * c_reg[jj] + iv * gv;
        c_reg[jj] = cn;
        hout[(size_t)(mrow0 + row) * kH + ntile * 48 + hc] = f2bf(ov * tanhf(cn));
      }
    }
    // ---- grid barrier (monotonic counter, release/acquire, agent scope) ----
    // BOUNDED spin: degrade to wrong answer, never hang the queue.
    __syncthreads();   // drains vmcnt before s_barrier -> block's stores at L2
    if (tid == 0) {
      __hip_atomic_fetch_add(bar, 1u, __ATOMIC_RELEASE, __HIP_MEMORY_SCOPE_AGENT);
      const u32 goal = (u32)(s + 1) * (u32)NBLK;
      u32 tries = 0;
      while (__hip_atomic_load(bar, __ATOMIC_RELAXED, __HIP_MEMORY_SCOPE_AGENT) < goal) {
        __builtin_amdgcn_s_sleep(8);
        if (++tries > 100000u) break;   // ~20 ms; normal wait is ~us
      }
      __threadfence();
    }
    __syncthreads();
  }
}

// ---------------------------------------------------------------- projection + L2 norm
__global__ __launch_bounds__(256) void k_proj(const u16* __restrict__ hlast,
                                              const float* __restrict__ pw,
                                              const float* __restrict__ pbv,
                                              float* __restrict__ out) {
  __shared__ float hs[8 * 768];
  __shared__ float wred[4 * 8];
  __shared__ float inv[8];
  const int tid = threadIdx.x;
  const int r0 = blockIdx.x * 8;
  for (int i = tid; i < 8 * 768; i += 256) hs[i] = bf2f(hlast[(size_t)r0 * 768 + i]);
  __syncthreads();
  float acc[8];
#pragma unroll
  for (int r = 0; r < 8; r++) acc[r] = 0.f;
  const float* wrow = pw + (size_t)tid * 768;
  for (int k = 0; k < 768; k++) {
    float w = wrow[k];
#pragma unroll
    for (int r = 0; r < 8; r++) acc[r] += hs[r * 768 + k] * w;
  }
  const float bv = pbv[tid];
#pragma unroll
  for (int r = 0; r < 8; r++) acc[r] += bv;
  const int lane = tid & 63, w4 = tid >> 6;
#pragma unroll
  for (int r = 0; r < 8; r++) {
    float v = acc[r] * acc[r];
#pragma unroll
    for (int off = 32; off > 0; off >>= 1) v += __shfl_xor(v, off);
    if (lane == 0) wred[w4 * 8 + r] = v;
  }
  __syncthreads();
  if (tid < 8) {
    float sum = wred[tid] + wred[8 + tid] + wred[16 + tid] + wred[24 + tid];
    inv[tid] = 1.f / sqrtf(sum);
  }
  __syncthreads();
#pragma unroll
  for (int r = 0; r < 8; r++) out[(size_t)(r0 + r) * 256 + tid] = acc[r] * inv[r];
}

// ---------------------------------------------------------------- host
extern "C" void kernel_launch(void* const* d_in, const int* in_sizes, int n_in,
                              void* d_out, int out_size, void* d_ws, size_t ws_size,
                              hipStream_t stream) {
  const float* x    = (const float*)d_in[0];
  const float* wih0 = (const float*)d_in[1];
  const float* whh0 = (const float*)d_in[2];
  const float* bi0  = (const float*)d_in[3];
  const float* bh0  = (const float*)d_in[4];
  const float* wih1 = (const float*)d_in[5];
  const float* whh1 = (const float*)d_in[6];
  const float* bi1  = (const float*)d_in[7];
  const float* bh1  = (const float*)d_in[8];
  const float* wih2 = (const float*)d_in[9];
  const float* whh2 = (const float*)d_in[10];
  const float* bi2  = (const float*)d_in[11];
  const float* bh2  = (const float*)d_in[12];
  const float* pw   = (const float*)d_in[13];
  const float* pbv  = (const float*)d_in[14];

  // Workspace-size guard: if insufficient, bail (clean wrong answer, no OOB).
  if (ws_size < WS_NEED) return;

  char* ws  = (char*)d_ws;
  u32*  bar = (u32*)(ws + 0);
  u16*  r0  = (u16*)(ws + OFF_R0);
  u16*  r1  = (u16*)(ws + OFF_R1);
  u16*  r2  = (u16*)(ws + OFF_R2);
  float* pb = (float*)(ws + OFF_PB);
  u16*  xT  = (u16*)(ws + OFF_XT);
  u16*  W0  = (u16*)(ws + OFF_W0);
  u16*  W1  = (u16*)(ws + OFF_W1);
  u16*  W2  = (u16*)(ws + OFF_W2);

  // zero barrier + rings (first OFF_PB bytes)
  hipLaunchKernelGGL(k_zero, dim3(512), dim3(256), 0, stream,
                     (uint4*)ws, (int)(OFF_PB / 16));
  hipLaunchKernelGGL(k_pack_w, dim3((L0N + 2 * L12N) / 256), dim3(256), 0, stream,
                     wih0, whh0, wih1, whh1, wih2, whh2, W0, W1, W2);
  hipLaunchKernelGGL(k_pack_b, dim3(36), dim3(256), 0, stream,
                     bi0, bh0, bi1, bh1, bi2, bh2, pb);
  hipLaunchKernelGGL(k_xT, dim3(kT * kB * 64 / 256), dim3(256), 0, stream, x, xT);

  // cooperative launch -> all 192 blocks co-resident (grid barrier is safe)
  {
    const u16* xTc = xT; const float* pbc = pb;
    const u16 *W0c = W0, *W1c = W1, *W2c = W2;
    u16 *r0m = r0, *r1m = r1, *r2m = r2; u32* barm = bar;
    void* kargs[] = {(void*)&xTc, (void*)&r0m, (void*)&r1m, (void*)&r2m,
                     (void*)&W0c, (void*)&W1c, (void*)&W2c, (void*)&pbc, (void*)&barm};
    hipLaunchCooperativeKernel((void*)k_lstm, dim3(NBLK), dim3(256), kargs, 0, stream);
  }

  hipLaunchKernelGGL(k_proj, dim3(64), dim3(256), 0, stream,
                     r2 + (size_t)3 * kB * kH, pw, pbv, (float*)d_out);
}

// Round 8
// 9786.879 us; speedup vs baseline: 2.7893x; 1.0962x over previous
//
#include <hip/hip_runtime.h>
#include <cstdint>
#include <cstddef>

using u16 = unsigned short;
using u32 = unsigned int;

typedef __attribute__((ext_vector_type(8)))  __bf16 bf16x8;
typedef __attribute__((ext_vector_type(16))) float  f32x16;

constexpr int kB   = 512;
constexpr int kT   = 180;
constexpr int kH   = 768;
constexpr int NBLK = 192;   // 3 layers * (4 m-tiles * 16 n-tiles)

constexpr int L0N  = 16 * 192 * 832;    // layer0 packed weight elems (26 chunks of 32)
constexpr int L12N = 16 * 192 * 1536;   // layer1/2 (48 chunks)

// h-ring: chunked layout [2 slots][24 kchunks][512 rows][32 k] bf16
constexpr int RING_SLOT_E = 24 * 512 * 32;               // 393,216 elems per slot
constexpr size_t RING_SZ  = (size_t)2 * RING_SLOT_E * 2; // 1,572,864 B

// workspace layout (bytes)
constexpr size_t OFF_R0  = 256;
constexpr size_t OFF_R1  = OFF_R0 + RING_SZ;
constexpr size_t OFF_R2  = OFF_R1 + RING_SZ;
constexpr size_t OFF_PB  = OFF_R2 + RING_SZ;             // zeroed region end
constexpr size_t OFF_XT  = OFF_PB + (size_t)3 * 3072 * 4;
constexpr size_t OFF_W0  = OFF_XT + (size_t)kT * kB * 64 * 2;
constexpr size_t OFF_W1  = OFF_W0 + (size_t)L0N * 2;
constexpr size_t OFF_W2  = OFF_W1 + (size_t)L12N * 2;
constexpr size_t WS_NEED = OFF_W2 + (size_t)L12N * 2;    // ~40.5 MB

#define CLB __asm__ volatile("" ::: "memory")

__device__ __forceinline__ float bf2f(u16 u) {
  union { u32 i; float f; } v; v.i = ((u32)u) << 16; return v.f;
}
__device__ __forceinline__ u16 f2bf(float f) {
  union { float f; u32 i; } v; v.f = f;
  u32 r = v.i + 0x7fffu + ((v.i >> 16) & 1u);
  return (u16)(r >> 16);
}

// async global->LDS, 16B per lane (wave-uniform LDS base + lane*16; dests lane-linear)
typedef __attribute__((address_space(1))) const u32 as1_u32;
typedef __attribute__((address_space(3))) u32 as3_u32;
__device__ __forceinline__ void gload_lds16(const u16* g, u16* l) {
  __builtin_amdgcn_global_load_lds((as1_u32*)g, (as3_u32*)l, 16, 0, 0);
}

// ---------------------------------------------------------------- zero
__global__ void k_zero(uint4* p, int n) {
  uint4 z = make_uint4(0u, 0u, 0u, 0u);
  for (int i = blockIdx.x * 256 + threadIdx.x; i < n; i += gridDim.x * 256) p[i] = z;
}

// ---------------------------------------------------------------- weight pack
// [ntile(16)][pcol(192)][K] bf16, K-contiguous per column.
// pcol = gate*48 + hc (i,f,g,o); global gate col = gate*768 + ntile*48 + hc.
// L0 K=832: k<40 w_ih0 | 40..63 zero | 64..831 w_hh0. L1/2 K=1536: k<768 w_ih else w_hh.
__global__ void k_pack_w(const float* __restrict__ wih0, const float* __restrict__ whh0,
                         const float* __restrict__ wih1, const float* __restrict__ whh1,
                         const float* __restrict__ wih2, const float* __restrict__ whh2,
                         u16* __restrict__ W0, u16* __restrict__ W1, u16* __restrict__ W2) {
  int idx = blockIdx.x * 256 + threadIdx.x;
  if (idx < L0N) {
    int col = idx / 832, k = idx - col * 832;
    int ntile = col / 192, p = col - ntile * 192;
    int g = p / 48, hc = p - g * 48;
    int gcol = g * 768 + ntile * 48 + hc;
    float v = (k < 40) ? wih0[gcol * 40 + k]
                       : ((k < 64) ? 0.f : whh0[(size_t)gcol * 768 + (k - 64)]);
    W0[idx] = f2bf(v);
  } else if (idx < L0N + L12N) {
    int li = idx - L0N;
    int col = li / 1536, k = li - col * 1536;
    int ntile = col / 192, p = col - ntile * 192;
    int g = p / 48, hc = p - g * 48;
    int gcol = g * 768 + ntile * 48 + hc;
    float v = (k < 768) ? wih1[(size_t)gcol * 768 + k] : whh1[(size_t)gcol * 768 + (k - 768)];
    W1[li] = f2bf(v);
  } else {
    int li = idx - (L0N + L12N);
    if (li < L12N) {
      int col = li / 1536, k = li - col * 1536;
      int ntile = col / 192, p = col - ntile * 192;
      int g = p / 48, hc = p - g * 48;
      int gcol = g * 768 + ntile * 48 + hc;
      float v = (k < 768) ? wih2[(size_t)gcol * 768 + k] : whh2[(size_t)gcol * 768 + (k - 768)];
      W2[li] = f2bf(v);
    }
  }
}

// ---------------------------------------------------------------- bias pack
__global__ void k_pack_b(const float* __restrict__ bi0, const float* __restrict__ bh0,
                         const float* __restrict__ bi1, const float* __restrict__ bh1,
                         const float* __restrict__ bi2, const float* __restrict__ bh2,
                         float* __restrict__ pbo) {
  int idx = blockIdx.x * 256 + threadIdx.x;   // 3*3072
  int l = idx / 3072, r = idx - l * 3072;
  int ntile = r / 192, p = r - ntile * 192;
  int g = p / 48, hc = p - g * 48;
  int gcol = g * 768 + ntile * 48 + hc;
  const float* bi = (l == 0) ? bi0 : ((l == 1) ? bi1 : bi2);
  const float* bh = (l == 0) ? bh0 : ((l == 1) ? bh1 : bh2);
  pbo[idx] = bi[gcol] + bh[gcol];
}

// ---------------------------------------------------------------- x transform
// [B,T,40] f32 -> chunked [T][2 kchunks][512][32] bf16 (64-pad)
__global__ void k_xT(const float* __restrict__ x, u16* __restrict__ xT) {
  int idx = blockIdx.x * 256 + threadIdx.x;    // 180*512*64
  int t = idx / (512 * 64);
  int r = idx - t * 512 * 64;
  int b = r >> 6, j = r & 63;
  float v = (j < 40) ? x[((size_t)b * 180 + t) * 40 + j] : 0.f;
  xT[(size_t)t * 32768 + (size_t)(j >> 5) * 16384 + b * 32 + (j & 31)] = f2bf(v);
}

// ---------------------------------------------------------------- persistent pipelined LSTM
// Grid 192x256 cooperative. XCD swizzle: the 4 m-tiles of one (layer,ntile) weight slice
// land on one XCD (bid%8) -> ~3.2MB weights/XCD < 4MB L2 -> weights L2-resident.
// Super-step s: layer l computes t = s - l; grid barrier per super-step.
//
// K-loop: R5's PROVEN homogeneous skeleton (glds-only vmcnt queue — R6/R7 showed mixed
// global_load + global_load_lds with partial vmcnt waits NaNs). Chunks of 32 k; BOTH A
// and B staged via glds into 3 rotating 20KB stages; 2 chunks (10 glds/thread) in
// flight. Per iter: wait vmcnt(5) [chunk c landed] -> s_barrier -> stage(c+2) ->
// ds_read+MFMA(c). Last iter waits vmcnt(0).
// Stage: A[128 rows][32k] @0 (8KB), B[192 cols][32k] @+8KB (12KB). Pitch 64B, 4 16B
// slots/row; slot sp holds k-octet sp^((row>>1)&3) -> lane-linear glds dests AND
// <=2-way (free) bank access on b128 frag reads (R5's ^(row&3) was 4-way: 6.75e8
// conflicts). Epilogue scratch [128][192] bf16 aliases stages. Total 62,208 B < 64KB.
__global__ __launch_bounds__(256, 2) void k_lstm(
    const u16* __restrict__ xT,
    u16* __restrict__ ring0, u16* __restrict__ ring1, u16* __restrict__ ring2,
    const u16* __restrict__ W0, const u16* __restrict__ W1, const u16* __restrict__ W2,
    const float* __restrict__ pb, u32* __restrict__ bar) {
  __shared__ __align__(16) unsigned char smem[61440 + 768];
  u16*   scr = (u16*)smem;                 // epilogue scratch [128][192] (aliases stages)
  float* pbs = (float*)(smem + 61440);

  const int tid = threadIdx.x;
  const int bid = blockIdx.x;
  // XCD swizzle: bid = 8*(4*(g/8) + mt) + g%8  (g = layer*16+ntile); bijective.
  const int xcd = bid & 7, j0 = bid >> 3;
  const int g_    = (j0 >> 2) * 8 + xcd;   // 0..47
  const int mt    = j0 & 3;
  const int layer = g_ >> 4;
  const int ntile = g_ & 15;
  const int mrow0 = mt * 128;

  const u16* Wl     = (layer == 0) ? W0 : ((layer == 1) ? W1 : W2);
  const int  Kl     = (layer == 0) ? 832 : 1536;
  const int  KcIn   = (layer == 0) ? 2 : 24;           // input k-chunks
  const int  nch    = (layer == 0) ? 26 : 48;
  const u16* inseq  = (layer == 1) ? ring0 : ring1;    // used by layers 1,2
  u16*       ringS  = (layer == 0) ? ring0 : ((layer == 1) ? ring1 : ring2);
  const u16* bbase0 = Wl + (size_t)(ntile * 192) * Kl;

  for (int i = tid; i < 192; i += 256) pbs[i] = pb[layer * 3072 + ntile * 192 + i];

  const int wid = tid >> 6, lane = tid & 63;
  const int wm = wid & 1, wn = wid >> 1;
  const int l31 = lane & 31, lhi = lane >> 5;

  float c_reg[24];
#pragma unroll
  for (int i = 0; i < 24; i++) c_reg[i] = 0.f;

  for (int s = 0; s < kT + 2; ++s) {
    const int t = s - layer;
    if (t >= 0 && t < kT) {
      f32x16 acc[2][3];
#pragma unroll
      for (int mi = 0; mi < 2; mi++)
#pragma unroll
        for (int ni = 0; ni < 3; ni++)
#pragma unroll
          for (int r = 0; r < 16; r++) acc[mi][ni][r] = 0.f;

      const u16* inbase  = (layer == 0) ? (xT + (size_t)t * 32768)
                                        : (inseq + (size_t)(t & 1) * RING_SLOT_E);
      const u16* recbase = ringS + (size_t)((t - 1) & 1) * RING_SLOT_E; // t=0 -> slot1 zeros

      // stage chunk c (32 k) into stage st: A 2 glds/thread + B 3 glds/thread
      auto stage = [&](int c, int st) {
        u16* sbA = (u16*)(smem + st * 20480);
        u16* sbB = sbA + 4096;               // +8192 bytes
        const u16* abase = (c < KcIn) ? (inbase + (size_t)c * 16384)
                                      : (recbase + (size_t)(c - KcIn) * 16384);
#pragma unroll
        for (int k = 0; k < 2; k++) {
          const int e = tid + k * 256;       // 0..511
          const int row = e >> 2, sp = e & 3;
          const int so = sp ^ ((row >> 1) & 3);
          gload_lds16(abase + (size_t)(mrow0 + row) * 32 + so * 8, sbA + (size_t)e * 8);
        }
        const u16* bb = bbase0 + c * 32;
#pragma unroll
        for (int k = 0; k < 3; k++) {
          const int e = tid + k * 256;       // 0..767
          const int col = e >> 2, sp = e & 3;
          const int so = sp ^ ((col >> 1) & 3);
          gload_lds16(bb + (size_t)col * Kl + so * 8, sbB + (size_t)e * 8);
        }
      };

      stage(0, 0);
      stage(1, 1);
      for (int c = 0; c < nch; ++c) {
        CLB;
        if (c == nch - 1) __builtin_amdgcn_s_waitcnt(0xF70);  // vmcnt(0)
        else              __builtin_amdgcn_s_waitcnt(0xF75);  // vmcnt(5): chunk c landed
        __builtin_amdgcn_s_barrier();
        CLB;
        if (c + 2 < nch) stage(c + 2, (c + 2) % 3);
        const u16* sA = (const u16*)(smem + (c % 3) * 20480);
        const u16* sB = sA + 4096;
        const int wsw = (l31 >> 1) & 3;
#pragma unroll
        for (int kk = 0; kk < 2; kk++) {
          const int sl = (((kk << 1) | lhi) ^ wsw) << 3;   // swizzled 16B slot
          bf16x8 a0 = *(const bf16x8*)(sA + (wm * 64 +      l31) * 32 + sl);
          bf16x8 a1 = *(const bf16x8*)(sA + (wm * 64 + 32 + l31) * 32 + sl);
          const int c0 = wn * 96 + l31;
          bf16x8 b0 = *(const bf16x8*)(sB + (c0     ) * 32 + sl);
          bf16x8 b1 = *(const bf16x8*)(sB + (c0 + 32) * 32 + sl);
          bf16x8 b2 = *(const bf16x8*)(sB + (c0 + 64) * 32 + sl);
          acc[0][0] = __builtin_amdgcn_mfma_f32_32x32x16_bf16(a0, b0, acc[0][0], 0, 0, 0);
          acc[0][1] = __builtin_amdgcn_mfma_f32_32x32x16_bf16(a0, b1, acc[0][1], 0, 0, 0);
          acc[0][2] = __builtin_amdgcn_mfma_f32_32x32x16_bf16(a0, b2, acc[0][2], 0, 0, 0);
          acc[1][0] = __builtin_amdgcn_mfma_f32_32x32x16_bf16(a1, b0, acc[1][0], 0, 0, 0);
          acc[1][1] = __builtin_amdgcn_mfma_f32_32x32x16_bf16(a1, b1, acc[1][1], 0, 0, 0);
          acc[1][2] = __builtin_amdgcn_mfma_f32_32x32x16_bf16(a1, b2, acc[1][2], 0, 0, 0);
        }
      }
      __syncthreads();   // all retired; protect stages before scr alias
      // epilogue: bias + nonlinearity (C/D: col=lane&31, row=(r&3)+8*(r>>2)+4*lhi)
#pragma unroll
      for (int mi = 0; mi < 2; mi++) {
#pragma unroll
        for (int ni = 0; ni < 3; ni++) {
          const int pcol = wn * 96 + ni * 32 + l31;
          const int gg = pcol / 48;
          const float bias = pbs[pcol];
#pragma unroll
          for (int r = 0; r < 16; r++) {
            const int rowl = wm * 64 + mi * 32 + (r & 3) + ((r >> 2) << 3) + (lhi << 2);
            float v = acc[mi][ni][r] + bias;
            v = (gg == 2) ? tanhf(v) : (1.f / (1.f + __expf(-v)));
            scr[rowl * 192 + pcol] = f2bf(v);
          }
        }
      }
      __syncthreads();
      // pointwise cell update; c in registers; h to chunked ring slot t&1
      u16* hout = ringS + (size_t)(t & 1) * RING_SLOT_E;
#pragma unroll
      for (int jj = 0; jj < 24; jj++) {
        const int idx = jj * 256 + tid;        // 6144 = 128 rows x 48 h-cols
        const int row = idx / 48;
        const int hc  = idx - row * 48;
        const float iv = bf2f(scr[row * 192       + hc]);
        const float fv = bf2f(scr[row * 192 +  48 + hc]);
        const float gv = bf2f(scr[row * 192 +  96 + hc]);
        const float ov = bf2f(scr[row * 192 + 144 + hc]);
        const float cn = fv * c_reg[jj] + iv * gv;
        c_reg[jj] = cn;
        const int colg = ntile * 48 + hc;
        hout[(size_t)(colg >> 5) * 16384 + (size_t)(mrow0 + row) * 32 + (colg & 31)]
            = f2bf(ov * tanhf(cn));
      }
    }
    // ---- grid barrier (monotonic counter; bounded spin: never hang the queue) ----
    __syncthreads();   // drains vmcnt -> block's h-stores at L2
    if (tid == 0) {
      __hip_atomic_fetch_add(bar, 1u, __ATOMIC_RELEASE, __HIP_MEMORY_SCOPE_AGENT);
      const u32 goal = (u32)(s + 1) * (u32)NBLK;
      u32 tries = 0;
      while (__hip_atomic_load(bar, __ATOMIC_RELAXED, __HIP_MEMORY_SCOPE_AGENT) < goal) {
        __builtin_amdgcn_s_sleep(8);
        if (++tries > 100000u) break;
      }
      __threadfence();
    }
    __syncthreads();
  }
}

// ---------------------------------------------------------------- projection + L2 norm
__global__ __launch_bounds__(256) void k_proj(const u16* __restrict__ hlast,
                                              const float* __restrict__ pw,
                                              const float* __restrict__ pbv,
                                              float* __restrict__ out) {
  __shared__ float hs[8 * 768];
  __shared__ float wred[4 * 8];
  __shared__ float inv[8];
  const int tid = threadIdx.x;
  const int r0 = blockIdx.x * 8;
  for (int i = tid; i < 8 * 768; i += 256) {
    const int b = i / 768, col = i - b * 768;   // chunked ring read
    hs[i] = bf2f(hlast[(size_t)(col >> 5) * 16384 + (size_t)(r0 + b) * 32 + (col & 31)]);
  }
  __syncthreads();
  float acc[8];
#pragma unroll
  for (int r = 0; r < 8; r++) acc[r] = 0.f;
  const float* wrow = pw + (size_t)tid * 768;
  for (int k = 0; k < 768; k++) {
    float w = wrow[k];
#pragma unroll
    for (int r = 0; r < 8; r++) acc[r] += hs[r * 768 + k] * w;
  }
  const float bv = pbv[tid];
#pragma unroll
  for (int r = 0; r < 8; r++) acc[r] += bv;
  const int lane = tid & 63, w4 = tid >> 6;
#pragma unroll
  for (int r = 0; r < 8; r++) {
    float v = acc[r] * acc[r];
#pragma unroll
    for (int off = 32; off > 0; off >>= 1) v += __shfl_xor(v, off);
    if (lane == 0) wred[w4 * 8 + r] = v;
  }
  __syncthreads();
  if (tid < 8) {
    float sum = wred[tid] + wred[8 + tid] + wred[16 + tid] + wred[24 + tid];
    inv[tid] = 1.f / sqrtf(sum);
  }
  __syncthreads();
#pragma unroll
  for (int r = 0; r < 8; r++) out[(size_t)(r0 + r) * 256 + tid] = acc[r] * inv[r];
}

// ---------------------------------------------------------------- host
extern "C" void kernel_launch(void* const* d_in, const int* in_sizes, int n_in,
                              void* d_out, int out_size, void* d_ws, size_t ws_size,
                              hipStream_t stream) {
  const float* x    = (const float*)d_in[0];
  const float* wih0 = (const float*)d_in[1];
  const float* whh0 = (const float*)d_in[2];
  const float* bi0  = (const float*)d_in[3];
  const float* bh0  = (const float*)d_in[4];
  const float* wih1 = (const float*)d_in[5];
  const float* whh1 = (const float*)d_in[6];
  const float* bi1  = (const float*)d_in[7];
  const float* bh1  = (const float*)d_in[8];
  const float* wih2 = (const float*)d_in[9];
  const float* whh2 = (const float*)d_in[10];
  const float* bi2  = (const float*)d_in[11];
  const float* bh2  = (const float*)d_in[12];
  const float* pw   = (const float*)d_in[13];
  const float* pbv  = (const float*)d_in[14];

  if (ws_size < WS_NEED) return;   // clean wrong answer, no OOB

  char* ws  = (char*)d_ws;
  u32*  bar = (u32*)(ws + 0);
  u16*  r0  = (u16*)(ws + OFF_R0);
  u16*  r1  = (u16*)(ws + OFF_R1);
  u16*  r2  = (u16*)(ws + OFF_R2);
  float* pb = (float*)(ws + OFF_PB);
  u16*  xT  = (u16*)(ws + OFF_XT);
  u16*  W0  = (u16*)(ws + OFF_W0);
  u16*  W1  = (u16*)(ws + OFF_W1);
  u16*  W2  = (u16*)(ws + OFF_W2);

  hipLaunchKernelGGL(k_zero, dim3(512), dim3(256), 0, stream,
                     (uint4*)ws, (int)(OFF_PB / 16));
  hipLaunchKernelGGL(k_pack_w, dim3((L0N + 2 * L12N + 255) / 256), dim3(256), 0, stream,
                     wih0, whh0, wih1, whh1, wih2, whh2, W0, W1, W2);
  hipLaunchKernelGGL(k_pack_b, dim3(36), dim3(256), 0, stream,
                     bi0, bh0, bi1, bh1, bi2, bh2, pb);
  hipLaunchKernelGGL(k_xT, dim3(kT * kB * 64 / 256), dim3(256), 0, stream, x, xT);

  {
    const u16* xTc = xT; const float* pbc = pb;
    const u16 *W0c = W0, *W1c = W1, *W2c = W2;
    u16 *r0m = r0, *r1m = r1, *r2m = r2; u32* barm = bar;
    void* kargs[] = {(void*)&xTc, (void*)&r0m, (void*)&r1m, (void*)&r2m,
                     (void*)&W0c, (void*)&W1c, (void*)&W2c, (void*)&pbc, (void*)&barm};
    hipLaunchCooperativeKernel((void*)k_lstm, dim3(NBLK), dim3(256), kargs, 0, stream);
  }

  hipLaunchKernelGGL(k_proj, dim3(64), dim3(256), 0, stream,
                     r2 + (size_t)((kT - 1) & 1) * RING_SLOT_E, pw, pbv, (float*)d_out);
}